// Round 1
// baseline (151.257 us; speedup 1.0000x reference)
//
#include <hip/hip_runtime.h>

// Flash-attention fwd: B=4,H=8,S=2048,Dh=64, f32 in/out, scale=1/sqrt(512).
// f16 MFMA (16x16x32), f32 accum. 4 waves/block, 16 q-rows/wave, KVBLK=64.

using half8  = __attribute__((ext_vector_type(8))) _Float16;
using half4  = __attribute__((ext_vector_type(4))) _Float16;
using half2v = __attribute__((ext_vector_type(2))) _Float16;
using f32x4  = __attribute__((ext_vector_type(4))) float;

#if __has_builtin(__builtin_amdgcn_exp2f)
#define EXP2F __builtin_amdgcn_exp2f
#else
#define EXP2F exp2f
#endif

#define SEQ   2048
#define DH    64
#define NBH   32
#define QB    64
#define KVB   64
#define NKVT  (SEQ / KVB)
// log2(e) / sqrt(512): fold softmax scale + base-2 conversion into Q
#define QSCALE (1.4426950408889634f / 22.627416997969522f)

__global__ __launch_bounds__(256)
void fattn_fwd(const float* __restrict__ Qg, const float* __restrict__ Kg,
               const float* __restrict__ Vg, float* __restrict__ Og)
{
    // K tile [kv=64][k=64], V^T tile [d=64][kv=64], P per-wave [q=16][kv=64]
    // all f16, row stride 128B, XOR-swizzled: byte ^= (row&7)<<4
    __shared__ __align__(16) _Float16 Klds[KVB * DH];
    __shared__ __align__(16) _Float16 VTlds[DH * KVB];
    __shared__ __align__(16) _Float16 Plds[4 * 16 * KVB];

    const int tid  = threadIdx.x;
    const int lane = tid & 63;
    const int wave = tid >> 6;
    const int l16  = lane & 15;
    const int lg   = lane >> 4;   // 0..3

    const int qb = blockIdx.x;    // q-tile: 0..31
    const int bh = blockIdx.y;    // batch*head: 0..31
    const size_t base = (size_t)bh * (SEQ * DH);

    // ---- Q fragments (MFMA A operand), pre-scaled.
    // A layout (16x16x32): row = lane&15, k = 8*(lane>>4)+i  (+32 per ks)
    half8 qfrag[2];
    {
        const int qrow = qb * QB + wave * 16 + l16;
        const float* qp = Qg + base + (size_t)qrow * DH + lg * 8;
#pragma unroll
        for (int ks = 0; ks < 2; ++ks) {
            f32x4 a = *(const f32x4*)(qp + ks * 32);
            f32x4 b = *(const f32x4*)(qp + ks * 32 + 4);
            half8 f;
#pragma unroll
            for (int i = 0; i < 4; ++i) f[i]     = (_Float16)(a[i] * QSCALE);
#pragma unroll
            for (int i = 0; i < 4; ++i) f[i + 4] = (_Float16)(b[i] * QSCALE);
            qfrag[ks] = f;
        }
    }

    // online-softmax state: 4 q-rows per lane (D-layout row = lg*4 + r)
    float m[4], l[4];
    f32x4 acc[4];
#pragma unroll
    for (int r = 0; r < 4; ++r) { m[r] = -INFINITY; l[r] = 0.f; }
#pragma unroll
    for (int d = 0; d < 4; ++d) acc[d] = f32x4{0.f, 0.f, 0.f, 0.f};

    char* kbase = (char*)Klds;
    char* vbase = (char*)VTlds;
    char* pbase = (char*)(Plds + wave * (16 * KVB));

    for (int kvt = 0; kvt < NKVT; ++kvt) {
        __syncthreads();   // previous iteration's LDS reads complete

        // ---- stage K tile (f32 -> f16, swizzled). 64 rows x 16 float4.
        {
            const float* kg = Kg + base + (size_t)kvt * (KVB * DH);
#pragma unroll
            for (int it = 0; it < 4; ++it) {
                int f   = it * 256 + tid;
                int row = f >> 4;         // 0..63
                int c4  = f & 15;         // float4 index in row
                f32x4 a = *(const f32x4*)(kg + (size_t)row * DH + c4 * 4);
                int byte = row * 128 + c4 * 8;
                byte ^= (row & 7) << 4;
                half4 h;
#pragma unroll
                for (int i = 0; i < 4; ++i) h[i] = (_Float16)a[i];
                *(half4*)(kbase + byte) = h;
            }
        }
        // ---- stage V^T (transpose during staging): VT[d][kv]
        {
            const float* vg = Vg + base + (size_t)kvt * (KVB * DH);
#pragma unroll
            for (int it = 0; it < 2; ++it) {
                int f   = it * 256 + tid;
                int kvp = f & 31;         // kv pair -> kv = 2*kvp
                int dg  = f >> 5;         // 0..15 -> d0 = 4*dg
                int kv  = kvp * 2;
                int d0  = dg * 4;
                f32x4 a = *(const f32x4*)(vg + (size_t)kv * DH + d0);
                f32x4 b = *(const f32x4*)(vg + (size_t)(kv + 1) * DH + d0);
#pragma unroll
                for (int i = 0; i < 4; ++i) {
                    int byte = (d0 + i) * 128 + kv * 2;
                    byte ^= ((d0 + i) & 7) << 4;
                    half2v h;
                    h[0] = (_Float16)a[i];
                    h[1] = (_Float16)b[i];
                    *(half2v*)(vbase + byte) = h;
                }
            }
        }
        __syncthreads();

        // ---- S = Q K^T : 4 kv-subtiles of 16, K-dim 64 = 2 MFMAs each.
        // B layout: col = lane&15 (kv within subtile), k = 8*(lane>>4)+i
        f32x4 s[4];
#pragma unroll
        for (int kvs = 0; kvs < 4; ++kvs) {
            f32x4 c = f32x4{0.f, 0.f, 0.f, 0.f};
#pragma unroll
            for (int ks = 0; ks < 2; ++ks) {
                int row  = kvs * 16 + l16;
                int byte = row * 128 + ks * 64 + lg * 16;
                byte ^= (row & 7) << 4;
                half8 kf = *(const half8*)(kbase + byte);
                c = __builtin_amdgcn_mfma_f32_16x16x32_f16(qfrag[ks], kf, c, 0, 0, 0);
            }
            s[kvs] = c;
        }

        // ---- online softmax. Row r's 64 scores live in 16 lanes (same lg).
        float alpha[4], lt[4];
#pragma unroll
        for (int r = 0; r < 4; ++r) {
            float mx = fmaxf(fmaxf(s[0][r], s[1][r]), fmaxf(s[2][r], s[3][r]));
            mx = fmaxf(mx, __shfl_xor(mx, 1));
            mx = fmaxf(mx, __shfl_xor(mx, 2));
            mx = fmaxf(mx, __shfl_xor(mx, 4));
            mx = fmaxf(mx, __shfl_xor(mx, 8));
            float mn = fmaxf(m[r], mx);
            alpha[r] = EXP2F(m[r] - mn);   // first tile: exp2(-inf)=0
            m[r] = mn;
            lt[r] = 0.f;
        }
#pragma unroll
        for (int kvs = 0; kvs < 4; ++kvs)
#pragma unroll
            for (int r = 0; r < 4; ++r) {
                float p = EXP2F(s[kvs][r] - m[r]);
                s[kvs][r] = p;
                lt[r] += p;
            }
#pragma unroll
        for (int r = 0; r < 4; ++r) {
            float t = lt[r];
            t += __shfl_xor(t, 1);
            t += __shfl_xor(t, 2);
            t += __shfl_xor(t, 4);
            t += __shfl_xor(t, 8);
            l[r] = l[r] * alpha[r] + t;
        }
#pragma unroll
        for (int d = 0; d < 4; ++d)
#pragma unroll
            for (int r = 0; r < 4; ++r)
                acc[d][r] *= alpha[r];

        // ---- P -> per-wave LDS (re-layout for PV A-fragment)
#pragma unroll
        for (int kvs = 0; kvs < 4; ++kvs)
#pragma unroll
            for (int r = 0; r < 4; ++r) {
                int row  = lg * 4 + r;
                int col  = kvs * 16 + l16;
                int byte = row * 128 + col * 2;
                byte ^= (row & 7) << 4;
                *(_Float16*)(pbase + byte) = (_Float16)s[kvs][r];
            }

        // ---- O += P @ V.  A = P[16q][kv], B = V[kv][16d] read from VT rows.
#pragma unroll
        for (int ks = 0; ks < 2; ++ks) {
            int pbyte = l16 * 128 + ks * 64 + lg * 16;
            pbyte ^= (l16 & 7) << 4;
            half8 pf = *(const half8*)(pbase + pbyte);
#pragma unroll
            for (int d = 0; d < 4; ++d) {
                int vrow  = d * 16 + l16;
                int vbyte = vrow * 128 + ks * 64 + lg * 16;
                vbyte ^= (vrow & 7) << 4;
                half8 vf = *(const half8*)(vbase + vbyte);
                acc[d] = __builtin_amdgcn_mfma_f32_16x16x32_f16(pf, vf, acc[d], 0, 0, 0);
            }
        }
    }

    // ---- epilogue: O / l.  D layout: row = lg*4+r, col = d*16+l16
#pragma unroll
    for (int r = 0; r < 4; ++r) {
        float invl = 1.f / l[r];
        int orow = qb * QB + wave * 16 + lg * 4 + r;
        float* op = Og + base + (size_t)orow * DH;
#pragma unroll
        for (int d = 0; d < 4; ++d)
            op[d * 16 + l16] = acc[d][r] * invl;
    }
}

extern "C" void kernel_launch(void* const* d_in, const int* in_sizes, int n_in,
                              void* d_out, int out_size, void* d_ws, size_t ws_size,
                              hipStream_t stream) {
    const float* q = (const float*)d_in[0];
    const float* k = (const float*)d_in[1];
    const float* v = (const float*)d_in[2];
    float* o = (float*)d_out;
    dim3 grid(SEQ / QB, NBH);
    fattn_fwd<<<grid, dim3(256, 1, 1), 0, stream>>>(q, k, v, o);
}